// Round 8
// baseline (329.391 us; speedup 1.0000x reference)
//
#include <hip/hip_runtime.h>
#include <hip/hip_bf16.h>

#define MM 256
#define HH 32
#define DD 128
#define PP 4096
#define NN 4096
#define LL 4352
#define NSTR 8
#define SPL 4

typedef __attribute__((ext_vector_type(8))) short short8;
typedef __attribute__((ext_vector_type(4))) float f32x4;

__device__ __forceinline__ unsigned short f2bf(float f) {
    union { float f; unsigned u; } x; x.f = f;
    unsigned u = x.u;
    return (unsigned short)((u + 0x7fffu + ((u >> 16) & 1u)) >> 16);
}

__device__ __forceinline__ float bf2f(unsigned short u) {
    union { unsigned u; float f; } x; x.u = ((unsigned)u) << 16;
    return x.f;
}

__device__ __forceinline__ f32x4 mfma16(short8 a, short8 b, f32x4 c) {
    return __builtin_amdgcn_mfma_f32_16x16x32_bf16(a, b, c, 0, 0, 0);
}

// ---- X fp32 -> xb bf16 [M][N] ----
__global__ __launch_bounds__(256) void conv_x_kernel(const float* __restrict__ src,
                                                     unsigned short* __restrict__ dst) {
    int i = blockIdx.x * 256 + threadIdx.x;
    long in0 = (long)i * 8;
    float4 f0 = *(const float4*)(src + in0);
    float4 f1 = *(const float4*)(src + in0 + 4);
    short8 v;
    v[0] = (short)f2bf(f0.x); v[1] = (short)f2bf(f0.y); v[2] = (short)f2bf(f0.z); v[3] = (short)f2bf(f0.w);
    v[4] = (short)f2bf(f1.x); v[5] = (short)f2bf(f1.y); v[6] = (short)f2bf(f1.z); v[7] = (short)f2bf(f1.w);
    *(short8*)(dst + in0) = v;
}

// ---- cache_K fp32 -> kcat bf16 [H][L][D] (head rows l<P) ----
__global__ __launch_bounds__(256) void conv_k_kernel(const float* __restrict__ src,
                                                     unsigned short* __restrict__ dst) {
    int i = blockIdx.x * 256 + threadIdx.x;
    int h = i >> 16;
    long in0 = (long)i * 8;
    float4 f0 = *(const float4*)(src + in0);
    float4 f1 = *(const float4*)(src + in0 + 4);
    short8 v;
    v[0] = (short)f2bf(f0.x); v[1] = (short)f2bf(f0.y); v[2] = (short)f2bf(f0.z); v[3] = (short)f2bf(f0.w);
    v[4] = (short)f2bf(f1.x); v[5] = (short)f2bf(f1.y); v[6] = (short)f2bf(f1.z); v[7] = (short)f2bf(f1.w);
    *(short8*)(dst + in0 + (long)h * (LL - PP) * DD) = v;
}

// ---- cache_V fp32 -> vT bf16 [H][D][L] (transpose, head l<P) ----
__global__ __launch_bounds__(256) void conv_vt_kernel(const float* __restrict__ src,
                                                      unsigned short* __restrict__ dst) {
    __shared__ unsigned short tile[64][65];
    int h = blockIdx.z, l0 = blockIdx.x * 64, d0 = blockIdx.y * 64;
    int t = threadIdx.x;
    int r = t >> 2, c0 = (t & 3) * 16;
    const float* sp = src + ((long)h * PP + l0 + r) * DD + d0 + c0;
#pragma unroll
    for (int j = 0; j < 16; j += 4) {
        float4 f = *(const float4*)(sp + j);
        tile[r][c0 + j + 0] = f2bf(f.x); tile[r][c0 + j + 1] = f2bf(f.y);
        tile[r][c0 + j + 2] = f2bf(f.z); tile[r][c0 + j + 3] = f2bf(f.w);
    }
    __syncthreads();
    unsigned short* dp = dst + ((long)h * DD + d0 + r) * LL + l0 + c0;
    short8 o0, o1;
#pragma unroll
    for (int j = 0; j < 8; ++j) o0[j] = (short)tile[c0 + j][r];
#pragma unroll
    for (int j = 0; j < 8; ++j) o1[j] = (short)tile[c0 + 8 + j][r];
    *(short8*)(dp) = o0;
    *(short8*)(dp + 8) = o1;
}

// ---- projections (R1-proven): 256x64 tile, BK=64, 2-deep named-stage reg prefetch ----
__device__ __forceinline__ void proj_body(unsigned short* As, unsigned short* Bs,
    const unsigned short* __restrict__ xp, const float* __restrict__ wp,
    int& k0, bool guard, short8 (&ar)[4], float4& b0, float4& b1,
    int arow, int ak0, int brow, int bk0, int mo, int no, int lg, int li,
    f32x4 (&acc)[4][2]) {
#pragma unroll
    for (int c = 0; c < 4; ++c) {
        int kb = (ak0 + c * 8) * 2;
        *(short8*)((char*)As + arow * 128 + (kb ^ ((arow & 7) << 4))) = ar[c];
    }
    {
        short8 v;
        v[0] = (short)f2bf(b0.x); v[1] = (short)f2bf(b0.y); v[2] = (short)f2bf(b0.z); v[3] = (short)f2bf(b0.w);
        v[4] = (short)f2bf(b1.x); v[5] = (short)f2bf(b1.y); v[6] = (short)f2bf(b1.z); v[7] = (short)f2bf(b1.w);
        int kb = bk0 * 2;
        *(short8*)((char*)Bs + brow * 128 + (kb ^ ((brow & 7) << 4))) = v;
    }
    __syncthreads();
    if (guard) {
#pragma unroll
        for (int c = 0; c < 4; ++c) ar[c] = *(const short8*)(xp + k0 + 128 + c * 8);
        b0 = *(const float4*)(wp + k0 + 128);
        b1 = *(const float4*)(wp + k0 + 132);
    }
#pragma unroll
    for (int kk = 0; kk < 2; ++kk) {
        short8 a[4], b[2];
        int kb = kk * 64 + lg * 16;
#pragma unroll
        for (int i = 0; i < 4; ++i) {
            int row = mo + i * 16 + li;
            a[i] = *(const short8*)((char*)As + row * 128 + (kb ^ ((row & 7) << 4)));
        }
#pragma unroll
        for (int j = 0; j < 2; ++j) {
            int row = no + j * 16 + li;
            b[j] = *(const short8*)((char*)Bs + row * 128 + (kb ^ ((row & 7) << 4)));
        }
#pragma unroll
        for (int i = 0; i < 4; ++i)
#pragma unroll
            for (int j = 0; j < 2; ++j)
                acc[i][j] = mfma16(a[i], b[j], acc[i][j]);
    }
    __syncthreads();
    k0 += 64;
}

__global__ __launch_bounds__(512) void proj_gemm_kernel(const unsigned short* __restrict__ xb,
    const float* __restrict__ Wq, const float* __restrict__ Wk, const float* __restrict__ Wv,
    float* __restrict__ qkvfP) {
    const int widx = blockIdx.z;
    const float* __restrict__ W = (widx == 0) ? Wq : (widx == 1 ? Wk : Wv);
    const int n0 = blockIdx.x * 64;
    const int ks = blockIdx.y;
    __shared__ unsigned short As[256 * 64];
    __shared__ unsigned short Bs[64 * 64];
    const int t = threadIdx.x;
    const int wv = t >> 6, lane = t & 63;
    const int lg = lane >> 4, li = lane & 15;
    const int mo = (wv >> 1) * 64, no = (wv & 1) * 32;
    f32x4 acc[4][2];
#pragma unroll
    for (int i = 0; i < 4; ++i)
#pragma unroll
        for (int j = 0; j < 2; ++j) acc[i][j] = (f32x4){0.f, 0.f, 0.f, 0.f};

    const int arow = t >> 1, ak0 = (t & 1) * 32;
    const int brow = t >> 3, bk0 = (t & 7) * 8;
    const unsigned short* xp = xb + (long)arow * NN + ak0;
    const float* wp = W + (long)(n0 + brow) * NN + bk0;

    int k0 = ks * 1024;
    short8 aA[4], aB[4];
    float4 bA0, bA1, bB0, bB1;
#pragma unroll
    for (int c = 0; c < 4; ++c) aA[c] = *(const short8*)(xp + k0 + c * 8);
    bA0 = *(const float4*)(wp + k0);
    bA1 = *(const float4*)(wp + k0 + 4);
#pragma unroll
    for (int c = 0; c < 4; ++c) aB[c] = *(const short8*)(xp + k0 + 64 + c * 8);
    bB0 = *(const float4*)(wp + k0 + 64);
    bB1 = *(const float4*)(wp + k0 + 68);

    for (int it2 = 0; it2 < 8; ++it2) {
        const bool guard = (it2 < 7);
        proj_body(As, Bs, xp, wp, k0, guard, aA, bA0, bA1,
                  arow, ak0, brow, bk0, mo, no, lg, li, acc);
        proj_body(As, Bs, xp, wp, k0, guard, aB, bB0, bB1,
                  arow, ak0, brow, bk0, mo, no, lg, li, acc);
    }

    float* dst = qkvfP + ((long)ks * 3 + widx) * MM * NN;
#pragma unroll
    for (int i = 0; i < 4; ++i)
#pragma unroll
        for (int j = 0; j < 2; ++j)
#pragma unroll
            for (int r = 0; r < 4; ++r) {
                int m = mo + i * 16 + lg * 4 + r;
                int n = n0 + no + j * 16 + li;
                dst[(long)m * NN + n] = acc[i][j][r];
            }
}

// ---- epilogue: sum 4 K-splits of q/k -> qb / kcat tail (bf16) ----
__global__ __launch_bounds__(256) void epi_qk_kernel(const float* __restrict__ qkvfP,
    unsigned short* __restrict__ qb, unsigned short* __restrict__ kcat) {
    int i = blockIdx.x * 256 + threadIdx.x;
    int w = i >> 17;
    int r = i & 131071;
    int m = r >> 9;
    int n = (r & 511) * 8;
    float4 f0 = {0,0,0,0}, f1 = {0,0,0,0};
#pragma unroll
    for (int s = 0; s < SPL; ++s) {
        const float* sp = qkvfP + ((long)s * 3 + w) * MM * NN + (long)m * NN + n;
        float4 a0 = *(const float4*)(sp);
        float4 a1 = *(const float4*)(sp + 4);
        f0.x += a0.x; f0.y += a0.y; f0.z += a0.z; f0.w += a0.w;
        f1.x += a1.x; f1.y += a1.y; f1.z += a1.z; f1.w += a1.w;
    }
    short8 v;
    v[0]=(short)f2bf(f0.x); v[1]=(short)f2bf(f0.y); v[2]=(short)f2bf(f0.z); v[3]=(short)f2bf(f0.w);
    v[4]=(short)f2bf(f1.x); v[5]=(short)f2bf(f1.y); v[6]=(short)f2bf(f1.z); v[7]=(short)f2bf(f1.w);
    int h = n >> 7, d = n & 127;
    if (w == 0) *(short8*)(qb + ((long)h * MM + m) * DD + d) = v;
    else        *(short8*)(kcat + ((long)h * LL + PP + m) * DD + d) = v;
}

// ---- epilogue: sum 4 K-splits of v -> vT tail (bf16, transposed) ----
__global__ __launch_bounds__(256) void epi_v_kernel(const float* __restrict__ qkvfP,
    unsigned short* __restrict__ vT) {
    __shared__ unsigned short tile[64][65];
    int m0 = blockIdx.x * 64, n0 = blockIdx.y * 64;
    int t = threadIdx.x;
    int r = t >> 2, c0 = (t & 3) * 16;
#pragma unroll
    for (int j = 0; j < 16; j += 4) {
        float4 f = {0,0,0,0};
#pragma unroll
        for (int s = 0; s < SPL; ++s) {
            const float* sp = qkvfP + ((long)s * 3 + 2) * MM * NN + (long)(m0 + r) * NN + n0 + c0 + j;
            float4 a = *(const float4*)(sp);
            f.x += a.x; f.y += a.y; f.z += a.z; f.w += a.w;
        }
        tile[r][c0 + j + 0] = f2bf(f.x); tile[r][c0 + j + 1] = f2bf(f.y);
        tile[r][c0 + j + 2] = f2bf(f.z); tile[r][c0 + j + 3] = f2bf(f.w);
    }
    __syncthreads();
    int h = n0 >> 7, d0 = n0 & 127;
    unsigned short* dp = vT + ((long)h * DD + d0 + r) * LL + PP + m0 + c0;
    short8 o0, o1;
#pragma unroll
    for (int j = 0; j < 8; ++j) o0[j] = (short)tile[c0 + j][r];
#pragma unroll
    for (int j = 0; j < 8; ++j) o1[j] = (short)tile[c0 + 8 + j][r];
    *(short8*)(dp) = o0;
    *(short8*)(dp + 8) = o1;
}

// ---- FUSED attention v3: ZERO barriers. K/V fed directly from global/L2 (tiles are
//      L2-resident; mb-swizzle gives XCD reuse). LDS only for wave-private cs/pbuf
//      transposes (within-wave write->read, proven pattern). Waves fully independent:
//      no barrier vmcnt drain, ~16 waves/CU, compiler pipelines loads freely. ----
__global__ __launch_bounds__(256) void attn_fused_kernel(const unsigned short* __restrict__ qb,
    const unsigned short* __restrict__ kcat, const unsigned short* __restrict__ vT,
    const float* __restrict__ noise, const float* __restrict__ tau,
    float* __restrict__ S1, float* __restrict__ S2,
    unsigned short* __restrict__ e2b, float* __restrict__ owsP) {
    // 1024 blocks = 8 XCD * 128; mb fastest -> the 4 mb-duplicates of each (h,ls)
    // K/V stripe land on the same XCD close in time -> L2 reuse.
    const int bid = blockIdx.x;
    const int swz = (bid & 7) * 128 + (bid >> 3);
    const int mb = swz & 3;
    const int ls = (swz >> 2) & 7;     // 8 stripes of 544 l
    const int h  = swz >> 5;           // 32 heads
    const int t = threadIdx.x, wv = t >> 6, lane = t & 63;
    const int lg = lane >> 4, li = lane & 15;
    __shared__ float cs[64][36];                 // wave-private scores (v1 stride: reads conflict-free)
    __shared__ unsigned short pbuf[64][40];      // wave-private e1 (v1 stride)
    const float inv_tau = 1.0f / tau[0];

    // Q fragments for this wave's 16 rows
    const int mA = mb * 64 + wv * 16 + li;
    const unsigned short* qp = qb + ((long)h * MM + mA) * DD + lg * 8;
    short8 aq[4];
#pragma unroll
    for (int dc = 0; dc < 4; ++dc) aq[dc] = *(const short8*)(qp + dc * 32);

    // exp-phase identity: 4 lanes per row, 8 consecutive l each
    const int row_l = t >> 2;
    const int col0 = (t & 3) * 8;
    const int mrow_g = mb * 64 + row_l;
    const float* np = noise + ((long)h * MM + mrow_g) * LL + ls * 544 + col0;
    unsigned short* e2p = e2b + ((long)h * MM + mrow_g) * LL + ls * 544 + col0;

    // direct K/V per-lane bases (replace LDS staging)
    const unsigned short* kp = kcat + ((long)h * LL + ls * 544 + li) * DD + lg * 8;
    const unsigned short* vp = vT + ((long)h * DD + li) * LL + ls * 544 + lg * 8;

    f32x4 acc[8];
#pragma unroll
    for (int dt = 0; dt < 8; ++dt) acc[dt] = (f32x4){0.f, 0.f, 0.f, 0.f};
    float s1t = 0.f, s2t = 0.f;

    for (int lc = 0; lc < 17; ++lc) {
        // ---- QK phase: K direct from global/L2 ----
        const unsigned short* kt = kp + (long)(lc * 32) * DD;
        short8 k0[4], k1[4];
#pragma unroll
        for (int dc = 0; dc < 4; ++dc) {
            k0[dc] = *(const short8*)(kt + dc * 32);
            k1[dc] = *(const short8*)(kt + 16 * DD + dc * 32);
        }
        f32x4 c0 = (f32x4){0.f,0.f,0.f,0.f}, c1 = (f32x4){0.f,0.f,0.f,0.f};
        __builtin_amdgcn_s_setprio(1);
#pragma unroll
        for (int dc = 0; dc < 4; ++dc) {
            c0 = mfma16(aq[dc], k0[dc], c0);
            c1 = mfma16(aq[dc], k1[dc], c1);
        }
        __builtin_amdgcn_s_setprio(0);
#pragma unroll
        for (int r = 0; r < 4; ++r) {
            cs[wv * 16 + lg * 4 + r][li] = c0[r];
            cs[wv * 16 + lg * 4 + r][16 + li] = c1[r];
        }
        // ---- EXP phase (wave-private cs; within-wave LDS ordering) ----
        float4 nA0 = *(const float4*)(np + lc * 32);
        float4 nA1 = *(const float4*)(np + lc * 32 + 4);
        float4 cva = *(const float4*)(&cs[row_l][col0]);
        float4 cvb = *(const float4*)(&cs[row_l][col0 + 4]);
        float cv[8] = {cva.x, cva.y, cva.z, cva.w, cvb.x, cvb.y, cvb.z, cvb.w};
        float nn[8] = {nA0.x, nA0.y, nA0.z, nA0.w, nA1.x, nA1.y, nA1.z, nA1.w};
        short8 v1, v2;
#pragma unroll
        for (int j = 0; j < 8; ++j) {
            float e1 = __expf(cv[j]);
            float e2 = __expf((cv[j] + nn[j]) * inv_tau);
            s1t += e1;
            s2t += e2;
            v1[j] = (short)f2bf(e1);
            v2[j] = (short)f2bf(e2);
        }
        *(short8*)(e2p + lc * 32) = v2;
        *(short8*)(&pbuf[row_l][col0]) = v1;        // e1 -> wave-private LDS
        // ---- PV phase: A = pbuf fragment, B = V direct from global/L2 ----
        {
            short8 pa = *(const short8*)(&pbuf[wv * 16 + li][lg * 8]);
            const unsigned short* vt0 = vp + lc * 32;
            short8 bv[8];
#pragma unroll
            for (int dt = 0; dt < 8; ++dt)
                bv[dt] = *(const short8*)(vt0 + (long)dt * 16 * LL);
            __builtin_amdgcn_s_setprio(1);
#pragma unroll
            for (int dt = 0; dt < 8; ++dt)
                acc[dt] = mfma16(pa, bv[dt], acc[dt]);
            __builtin_amdgcn_s_setprio(0);
        }
    }

    // 4 lanes per row -> row sums
    s1t += __shfl_xor(s1t, 1); s1t += __shfl_xor(s1t, 2);
    s2t += __shfl_xor(s2t, 1); s2t += __shfl_xor(s2t, 2);
    if ((t & 3) == 0) {
        atomicAdd(&S1[h * MM + mrow_g], s1t);
        atomicAdd(&S2[h * MM + mrow_g], s2t);
    }

    // write PV stripe partials
    const int mD = mb * 64 + wv * 16 + lg * 4;
    float* op = owsP + ((long)ls * HH + h) * MM * DD;
#pragma unroll
    for (int dt = 0; dt < 8; ++dt)
#pragma unroll
        for (int r = 0; r < 4; ++r)
            op[(long)(mD + r) * DD + dt * 16 + li] = acc[dt][r];
}

// ---- finalize: sum stripe partials, /S1 -> out; invS2 ----
__global__ __launch_bounds__(256) void finalize_o_kernel(const float* __restrict__ owsP,
    const float* __restrict__ S1, const float* __restrict__ S2,
    float* __restrict__ out, float* __restrict__ invS2) {
    int i = blockIdx.x * 256 + threadIdx.x;
    int hm = i >> 5;
    int d4 = (i & 31) * 4;
    int h = hm >> 8, m = hm & 255;
    float4 s = {0,0,0,0};
#pragma unroll
    for (int st = 0; st < NSTR; ++st) {
        const float4 v = *(const float4*)(owsP + ((long)st * HH * MM + hm) * DD + d4);
        s.x += v.x; s.y += v.y; s.z += v.z; s.w += v.w;
    }
    float inv = 1.0f / S1[hm];
    float4 o;
    o.x = s.x * inv; o.y = s.y * inv; o.z = s.z * inv; o.w = s.w * inv;
    *(float4*)(out + (long)m * NN + h * DD + d4) = o;
    if ((i & 31) == 0) invS2[hm] = 1.0f / S2[hm];
}

// ---- pass 2: c_out[h][l] = sum_m e2[h][m][l] * invS2[h][m] ----
__global__ __launch_bounds__(256) void attn_p2_kernel(const unsigned short* __restrict__ e2b,
    const float* __restrict__ invS2, float* __restrict__ cout) {
    const int h = blockIdx.y;
    const int l = blockIdx.x * 256 + threadIdx.x;
    const unsigned short* ep = e2b + (long)h * MM * LL + l;
    const float* is2 = invS2 + h * MM;
    float acc0 = 0.f, acc1 = 0.f, acc2 = 0.f, acc3 = 0.f;
    for (int m = 0; m < MM; m += 4) {
        acc0 += bf2f(__builtin_nontemporal_load(ep + (long)(m + 0) * LL)) * is2[m + 0];
        acc1 += bf2f(__builtin_nontemporal_load(ep + (long)(m + 1) * LL)) * is2[m + 1];
        acc2 += bf2f(__builtin_nontemporal_load(ep + (long)(m + 2) * LL)) * is2[m + 2];
        acc3 += bf2f(__builtin_nontemporal_load(ep + (long)(m + 3) * LL)) * is2[m + 3];
    }
    cout[(long)h * LL + l] = (acc0 + acc1) + (acc2 + acc3);
}

extern "C" void kernel_launch(void* const* d_in, const int* in_sizes, int n_in,
                              void* d_out, int out_size, void* d_ws, size_t ws_size,
                              hipStream_t stream) {
    const float* X     = (const float*)d_in[0];
    const float* Wq    = (const float*)d_in[1];
    const float* Wk    = (const float*)d_in[2];
    const float* Wv    = (const float*)d_in[3];
    const float* cK    = (const float*)d_in[4];
    const float* cV    = (const float*)d_in[5];
    const float* tau   = (const float*)d_in[6];
    const float* noise = (const float*)d_in[7];
    float* out = (float*)d_out;

    char* ws = (char*)d_ws;
    size_t off = 0;
    unsigned short* qb   = (unsigned short*)(ws + off); off += (size_t)HH * MM * DD * 2;
    unsigned short* kcat = (unsigned short*)(ws + off); off += (size_t)HH * LL * DD * 2;
    unsigned short* vT   = (unsigned short*)(ws + off); off += (size_t)HH * LL * DD * 2;
    float* S1    = (float*)(ws + off); off += (size_t)HH * MM * 4;
    float* S2    = (float*)(ws + off); off += (size_t)HH * MM * 4;
    float* invS2 = (float*)(ws + off); off += (size_t)HH * MM * 4;
    float* owsP  = (float*)(ws + off); off += (size_t)NSTR * HH * MM * DD * 4;
    unsigned short* xb = (unsigned short*)(ws + off); off += (size_t)MM * NN * 2;
    float* qkvfP = (float*)(ws + off); off += (size_t)SPL * 3 * MM * NN * 4;
    unsigned short* e2b = (unsigned short*)(ws + off); off += (size_t)HH * MM * LL * 2;

    hipMemsetAsync(S1, 0, 2 * (size_t)HH * MM * 4, stream);

    conv_x_kernel<<<512, 256, 0, stream>>>(X, xb);
    conv_k_kernel<<<8192, 256, 0, stream>>>(cK, kcat);
    conv_vt_kernel<<<dim3(64, 2, 32), 256, 0, stream>>>(cV, vT);
    proj_gemm_kernel<<<dim3(64, SPL, 3), 512, 0, stream>>>(xb, Wq, Wk, Wv, qkvfP);
    epi_qk_kernel<<<1024, 256, 0, stream>>>(qkvfP, qb, kcat);
    epi_v_kernel<<<dim3(4, 64), 256, 0, stream>>>(qkvfP, vT);
    attn_fused_kernel<<<1024, 256, 0, stream>>>(qb, kcat, vT, noise, tau, S1, S2, e2b, owsP);
    finalize_o_kernel<<<1024, 256, 0, stream>>>(owsP, S1, S2, out, invS2);
    attn_p2_kernel<<<dim3(17, 32), 256, 0, stream>>>(e2b, invS2, out + (size_t)MM * NN);
}

// Round 9
// 243.767 us; speedup vs baseline: 1.3513x; 1.3513x over previous
//
#include <hip/hip_runtime.h>
#include <hip/hip_bf16.h>

#define MM 256
#define HH 32
#define DD 128
#define PP 4096
#define NN 4096
#define LL 4352
#define NSTR 8
#define SPL 4

typedef __attribute__((ext_vector_type(8))) short short8;
typedef __attribute__((ext_vector_type(4))) float f32x4;

__device__ __forceinline__ unsigned short f2bf(float f) {
    union { float f; unsigned u; } x; x.f = f;
    unsigned u = x.u;
    return (unsigned short)((u + 0x7fffu + ((u >> 16) & 1u)) >> 16);
}

__device__ __forceinline__ float bf2f(unsigned short u) {
    union { unsigned u; float f; } x; x.u = ((unsigned)u) << 16;
    return x.f;
}

__device__ __forceinline__ f32x4 mfma16(short8 a, short8 b, f32x4 c) {
    return __builtin_amdgcn_mfma_f32_16x16x32_bf16(a, b, c, 0, 0, 0);
}

// ---- X fp32 -> xb bf16 [M][N] ----
__global__ __launch_bounds__(256) void conv_x_kernel(const float* __restrict__ src,
                                                     unsigned short* __restrict__ dst) {
    int i = blockIdx.x * 256 + threadIdx.x;
    long in0 = (long)i * 8;
    float4 f0 = *(const float4*)(src + in0);
    float4 f1 = *(const float4*)(src + in0 + 4);
    short8 v;
    v[0] = (short)f2bf(f0.x); v[1] = (short)f2bf(f0.y); v[2] = (short)f2bf(f0.z); v[3] = (short)f2bf(f0.w);
    v[4] = (short)f2bf(f1.x); v[5] = (short)f2bf(f1.y); v[6] = (short)f2bf(f1.z); v[7] = (short)f2bf(f1.w);
    *(short8*)(dst + in0) = v;
}

// ---- cache_K fp32 -> kcat bf16 [H][L][D] (head rows l<P) ----
__global__ __launch_bounds__(256) void conv_k_kernel(const float* __restrict__ src,
                                                     unsigned short* __restrict__ dst) {
    int i = blockIdx.x * 256 + threadIdx.x;
    int h = i >> 16;
    long in0 = (long)i * 8;
    float4 f0 = *(const float4*)(src + in0);
    float4 f1 = *(const float4*)(src + in0 + 4);
    short8 v;
    v[0] = (short)f2bf(f0.x); v[1] = (short)f2bf(f0.y); v[2] = (short)f2bf(f0.z); v[3] = (short)f2bf(f0.w);
    v[4] = (short)f2bf(f1.x); v[5] = (short)f2bf(f1.y); v[6] = (short)f2bf(f1.z); v[7] = (short)f2bf(f1.w);
    *(short8*)(dst + in0 + (long)h * (LL - PP) * DD) = v;
}

// ---- cache_V fp32 -> vT bf16 [H][D][L] (transpose, head l<P) ----
__global__ __launch_bounds__(256) void conv_vt_kernel(const float* __restrict__ src,
                                                      unsigned short* __restrict__ dst) {
    __shared__ unsigned short tile[64][65];
    int h = blockIdx.z, l0 = blockIdx.x * 64, d0 = blockIdx.y * 64;
    int t = threadIdx.x;
    int r = t >> 2, c0 = (t & 3) * 16;
    const float* sp = src + ((long)h * PP + l0 + r) * DD + d0 + c0;
#pragma unroll
    for (int j = 0; j < 16; j += 4) {
        float4 f = *(const float4*)(sp + j);
        tile[r][c0 + j + 0] = f2bf(f.x); tile[r][c0 + j + 1] = f2bf(f.y);
        tile[r][c0 + j + 2] = f2bf(f.z); tile[r][c0 + j + 3] = f2bf(f.w);
    }
    __syncthreads();
    unsigned short* dp = dst + ((long)h * DD + d0 + r) * LL + l0 + c0;
    short8 o0, o1;
#pragma unroll
    for (int j = 0; j < 8; ++j) o0[j] = (short)tile[c0 + j][r];
#pragma unroll
    for (int j = 0; j < 8; ++j) o1[j] = (short)tile[c0 + 8 + j][r];
    *(short8*)(dp) = o0;
    *(short8*)(dp + 8) = o1;
}

// ---- projections (R1-proven): 256x64 tile, BK=64, 2-deep named-stage reg prefetch ----
__device__ __forceinline__ void proj_body(unsigned short* As, unsigned short* Bs,
    const unsigned short* __restrict__ xp, const float* __restrict__ wp,
    int& k0, bool guard, short8 (&ar)[4], float4& b0, float4& b1,
    int arow, int ak0, int brow, int bk0, int mo, int no, int lg, int li,
    f32x4 (&acc)[4][2]) {
#pragma unroll
    for (int c = 0; c < 4; ++c) {
        int kb = (ak0 + c * 8) * 2;
        *(short8*)((char*)As + arow * 128 + (kb ^ ((arow & 7) << 4))) = ar[c];
    }
    {
        short8 v;
        v[0] = (short)f2bf(b0.x); v[1] = (short)f2bf(b0.y); v[2] = (short)f2bf(b0.z); v[3] = (short)f2bf(b0.w);
        v[4] = (short)f2bf(b1.x); v[5] = (short)f2bf(b1.y); v[6] = (short)f2bf(b1.z); v[7] = (short)f2bf(b1.w);
        int kb = bk0 * 2;
        *(short8*)((char*)Bs + brow * 128 + (kb ^ ((brow & 7) << 4))) = v;
    }
    __syncthreads();
    if (guard) {
#pragma unroll
        for (int c = 0; c < 4; ++c) ar[c] = *(const short8*)(xp + k0 + 128 + c * 8);
        b0 = *(const float4*)(wp + k0 + 128);
        b1 = *(const float4*)(wp + k0 + 132);
    }
#pragma unroll
    for (int kk = 0; kk < 2; ++kk) {
        short8 a[4], b[2];
        int kb = kk * 64 + lg * 16;
#pragma unroll
        for (int i = 0; i < 4; ++i) {
            int row = mo + i * 16 + li;
            a[i] = *(const short8*)((char*)As + row * 128 + (kb ^ ((row & 7) << 4)));
        }
#pragma unroll
        for (int j = 0; j < 2; ++j) {
            int row = no + j * 16 + li;
            b[j] = *(const short8*)((char*)Bs + row * 128 + (kb ^ ((row & 7) << 4)));
        }
#pragma unroll
        for (int i = 0; i < 4; ++i)
#pragma unroll
            for (int j = 0; j < 2; ++j)
                acc[i][j] = mfma16(a[i], b[j], acc[i][j]);
    }
    __syncthreads();
    k0 += 64;
}

__global__ __launch_bounds__(512) void proj_gemm_kernel(const unsigned short* __restrict__ xb,
    const float* __restrict__ Wq, const float* __restrict__ Wk, const float* __restrict__ Wv,
    float* __restrict__ qkvfP) {
    const int widx = blockIdx.z;
    const float* __restrict__ W = (widx == 0) ? Wq : (widx == 1 ? Wk : Wv);
    const int n0 = blockIdx.x * 64;
    const int ks = blockIdx.y;
    __shared__ unsigned short As[256 * 64];
    __shared__ unsigned short Bs[64 * 64];
    const int t = threadIdx.x;
    const int wv = t >> 6, lane = t & 63;
    const int lg = lane >> 4, li = lane & 15;
    const int mo = (wv >> 1) * 64, no = (wv & 1) * 32;
    f32x4 acc[4][2];
#pragma unroll
    for (int i = 0; i < 4; ++i)
#pragma unroll
        for (int j = 0; j < 2; ++j) acc[i][j] = (f32x4){0.f, 0.f, 0.f, 0.f};

    const int arow = t >> 1, ak0 = (t & 1) * 32;
    const int brow = t >> 3, bk0 = (t & 7) * 8;
    const unsigned short* xp = xb + (long)arow * NN + ak0;
    const float* wp = W + (long)(n0 + brow) * NN + bk0;

    int k0 = ks * 1024;
    short8 aA[4], aB[4];
    float4 bA0, bA1, bB0, bB1;
#pragma unroll
    for (int c = 0; c < 4; ++c) aA[c] = *(const short8*)(xp + k0 + c * 8);
    bA0 = *(const float4*)(wp + k0);
    bA1 = *(const float4*)(wp + k0 + 4);
#pragma unroll
    for (int c = 0; c < 4; ++c) aB[c] = *(const short8*)(xp + k0 + 64 + c * 8);
    bB0 = *(const float4*)(wp + k0 + 64);
    bB1 = *(const float4*)(wp + k0 + 68);

    for (int it2 = 0; it2 < 8; ++it2) {
        const bool guard = (it2 < 7);
        proj_body(As, Bs, xp, wp, k0, guard, aA, bA0, bA1,
                  arow, ak0, brow, bk0, mo, no, lg, li, acc);
        proj_body(As, Bs, xp, wp, k0, guard, aB, bB0, bB1,
                  arow, ak0, brow, bk0, mo, no, lg, li, acc);
    }

    float* dst = qkvfP + ((long)ks * 3 + widx) * MM * NN;
#pragma unroll
    for (int i = 0; i < 4; ++i)
#pragma unroll
        for (int j = 0; j < 2; ++j)
#pragma unroll
            for (int r = 0; r < 4; ++r) {
                int m = mo + i * 16 + lg * 4 + r;
                int n = n0 + no + j * 16 + li;
                dst[(long)m * NN + n] = acc[i][j][r];
            }
}

// ---- epilogue: sum 4 K-splits of q/k -> qb / kcat tail (bf16) ----
__global__ __launch_bounds__(256) void epi_qk_kernel(const float* __restrict__ qkvfP,
    unsigned short* __restrict__ qb, unsigned short* __restrict__ kcat) {
    int i = blockIdx.x * 256 + threadIdx.x;
    int w = i >> 17;
    int r = i & 131071;
    int m = r >> 9;
    int n = (r & 511) * 8;
    float4 f0 = {0,0,0,0}, f1 = {0,0,0,0};
#pragma unroll
    for (int s = 0; s < SPL; ++s) {
        const float* sp = qkvfP + ((long)s * 3 + w) * MM * NN + (long)m * NN + n;
        float4 a0 = *(const float4*)(sp);
        float4 a1 = *(const float4*)(sp + 4);
        f0.x += a0.x; f0.y += a0.y; f0.z += a0.z; f0.w += a0.w;
        f1.x += a1.x; f1.y += a1.y; f1.z += a1.z; f1.w += a1.w;
    }
    short8 v;
    v[0]=(short)f2bf(f0.x); v[1]=(short)f2bf(f0.y); v[2]=(short)f2bf(f0.z); v[3]=(short)f2bf(f0.w);
    v[4]=(short)f2bf(f1.x); v[5]=(short)f2bf(f1.y); v[6]=(short)f2bf(f1.z); v[7]=(short)f2bf(f1.w);
    int h = n >> 7, d = n & 127;
    if (w == 0) *(short8*)(qb + ((long)h * MM + m) * DD + d) = v;
    else        *(short8*)(kcat + ((long)h * LL + PP + m) * DD + d) = v;
}

// ---- epilogue: sum 4 K-splits of v -> vT tail (bf16, transposed) ----
__global__ __launch_bounds__(256) void epi_v_kernel(const float* __restrict__ qkvfP,
    unsigned short* __restrict__ vT) {
    __shared__ unsigned short tile[64][65];
    int m0 = blockIdx.x * 64, n0 = blockIdx.y * 64;
    int t = threadIdx.x;
    int r = t >> 2, c0 = (t & 3) * 16;
#pragma unroll
    for (int j = 0; j < 16; j += 4) {
        float4 f = {0,0,0,0};
#pragma unroll
        for (int s = 0; s < SPL; ++s) {
            const float* sp = qkvfP + ((long)s * 3 + 2) * MM * NN + (long)(m0 + r) * NN + n0 + c0 + j;
            float4 a = *(const float4*)(sp);
            f.x += a.x; f.y += a.y; f.z += a.z; f.w += a.w;
        }
        tile[r][c0 + j + 0] = f2bf(f.x); tile[r][c0 + j + 1] = f2bf(f.y);
        tile[r][c0 + j + 2] = f2bf(f.z); tile[r][c0 + j + 3] = f2bf(f.w);
    }
    __syncthreads();
    int h = n0 >> 7, d0 = n0 & 127;
    unsigned short* dp = vT + ((long)h * DD + d0 + r) * LL + PP + m0 + c0;
    short8 o0, o1;
#pragma unroll
    for (int j = 0; j < 8; ++j) o0[j] = (short)tile[c0 + j][r];
#pragma unroll
    for (int j = 0; j < 8; ++j) o1[j] = (short)tile[c0 + 8 + j][r];
    *(short8*)(dp) = o0;
    *(short8*)(dp + 8) = o1;
}

// ---- FUSED attention v4: R7 structure (LDS-staged K/V, dbuf, 1 barrier/iter, swizzles,
//      setprio) + cs/pbuf UNION -> LDS 40960 exactly -> 4 blocks/CU single dispatch round.
//      Union safety: cs and pbuf are wave-private (rows wv*16..wv*16+15) and accessed
//      strictly sequentially in program order per wave (write cs -> read cs -> write pbuf
//      -> read pbuf); same-array aliasing keeps LDS op order. ----
__global__ __launch_bounds__(256) void attn_fused_kernel(const unsigned short* __restrict__ qb,
    const unsigned short* __restrict__ kcat, const unsigned short* __restrict__ vT,
    const float* __restrict__ noise, const float* __restrict__ tau,
    float* __restrict__ S1, float* __restrict__ S2,
    unsigned short* __restrict__ e2b, float* __restrict__ owsP) {
    // 1024 blocks = 8 XCD * 128; mb fastest -> the 4 mb-duplicates of each (h,ls)
    // K/V stripe land on the same XCD close in time -> L2 reuse.
    const int bid = blockIdx.x;
    const int swz = (bid & 7) * 128 + (bid >> 3);
    const int mb = swz & 3;
    const int ls = (swz >> 2) & 7;     // 8 stripes of 544 l
    const int h  = swz >> 5;           // 32 heads
    const int t = threadIdx.x, wv = t >> 6, lane = t & 63;
    const int lg = lane >> 4, li = lane & 15;
    __shared__ unsigned short kbuf[2][32][128];  // 16 KB
    __shared__ unsigned short vbuf[2][128][32];  // 16 KB
    __shared__ float csbuf[64][32];              // 8 KB; pbuf aliases first 64B of each row
    const float inv_tau = 1.0f / tau[0];

    // Q fragments for this wave's 16 rows
    const int mA = mb * 64 + wv * 16 + li;
    const unsigned short* qp = qb + ((long)h * MM + mA) * DD + lg * 8;
    short8 aq[4];
#pragma unroll
    for (int dc = 0; dc < 4; ++dc) aq[dc] = *(const short8*)(qp + dc * 32);

    // exp-phase identity: 4 lanes per row, 8 consecutive l each
    const int row_l = t >> 2;
    const int col0 = (t & 3) * 8;
    const int mrow_g = mb * 64 + row_l;
    const float* np = noise + ((long)h * MM + mrow_g) * LL + ls * 544 + col0;
    unsigned short* e2p = e2b + ((long)h * MM + mrow_g) * LL + ls * 544 + col0;
    // swizzled cs read cols (float index, chunk bits ^ row&7)
    const int csr0 = col0 ^ ((row_l & 7) << 2);
    const int csr1 = (col0 + 4) ^ ((row_l & 7) << 2);
    // pbuf (union) write byte offset within row: 16B chunk (t&3)^(row_l&3)
    const int pwB = ((t & 3) ^ (row_l & 3)) * 16;

    // K staging: thread t covers l-row srow (0..31), chunks 2(t&7), 2(t&7)+1
    const int srow = t >> 3;
    const int kc0 = (t & 7) * 2, kc1 = kc0 + 1;
    const int kwo0 = (kc0 ^ (srow & 7)) * 8, kwo1 = (kc1 ^ (srow & 7)) * 8;
    const unsigned short* ksrc = kcat + ((long)h * LL + ls * 544 + srow) * DD + (t & 7) * 16;
    // V staging: thread t covers d-row vrow (0..127), chunks 2(t&1), 2(t&1)+1
    const int vrow = t >> 1;
    const int vc0 = (t & 1) * 2, vc1 = vc0 + 1;
    const int vwo0 = (vc0 ^ (vrow & 3)) * 8, vwo1 = (vc1 ^ (vrow & 3)) * 8;
    const unsigned short* vsrc = vT + ((long)h * DD + vrow) * LL + ls * 544 + (t & 1) * 16;
    // swizzled PV/pbuf read chunk (lg ^ li&3), byte offset
    const int vro = (lg ^ (li & 3)) * 8;
    const int prB = (lg ^ (li & 3)) * 16;

    // prologue: stage tile 0 (K and V)
    {
        short8 k0 = *(const short8*)(ksrc);
        short8 k1 = *(const short8*)(ksrc + 8);
        *(short8*)(&kbuf[0][srow][kwo0]) = k0;
        *(short8*)(&kbuf[0][srow][kwo1]) = k1;
        short8 v0 = *(const short8*)(vsrc);
        short8 v1 = *(const short8*)(vsrc + 8);
        *(short8*)(&vbuf[0][vrow][vwo0]) = v0;
        *(short8*)(&vbuf[0][vrow][vwo1]) = v1;
    }
    // noise prefetch: tiles 0 and 1
    float4 nA0 = *(const float4*)(np);
    float4 nA1 = *(const float4*)(np + 4);
    float4 nB0 = *(const float4*)(np + 32);
    float4 nB1 = *(const float4*)(np + 36);

    f32x4 acc[8];
#pragma unroll
    for (int dt = 0; dt < 8; ++dt) acc[dt] = (f32x4){0.f, 0.f, 0.f, 0.f};
    float s1t = 0.f, s2t = 0.f;
    int cur = 0;
    __syncthreads();

    for (int lc = 0; lc < 17; ++lc) {
        // issue next-tile global loads early (overlap with MFMA + exp below)
        short8 kn0, kn1, vn0, vn1;
        if (lc < 16) {
            const unsigned short* pk = ksrc + (long)((lc + 1) * 32) * DD;
            kn0 = *(const short8*)(pk);
            kn1 = *(const short8*)(pk + 8);
            const unsigned short* pv = vsrc + (lc + 1) * 32;
            vn0 = *(const short8*)(pv);
            vn1 = *(const short8*)(pv + 8);
        }
        // ---- QK phase from kbuf (swizzled reads: chunk (dc*4+lg) ^ (li&7)) ----
        f32x4 c0 = (f32x4){0.f,0.f,0.f,0.f}, c1 = (f32x4){0.f,0.f,0.f,0.f};
        __builtin_amdgcn_s_setprio(1);
#pragma unroll
        for (int dc = 0; dc < 4; ++dc) {
            const int kro = ((dc * 4 + lg) ^ (li & 7)) * 8;
            short8 k0 = *(const short8*)(&kbuf[cur][li][kro]);
            short8 k1 = *(const short8*)(&kbuf[cur][16 + li][kro]);
            c0 = mfma16(aq[dc], k0, c0);
            c1 = mfma16(aq[dc], k1, c1);
        }
        __builtin_amdgcn_s_setprio(0);
#pragma unroll
        for (int r = 0; r < 4; ++r) {
            const int csr = wv * 16 + lg * 4 + r;
            const int cx = (csr & 7) << 2;
            csbuf[csr][li ^ cx] = c0[r];
            csbuf[csr][(16 + li) ^ cx] = c1[r];
        }
        // ---- EXP phase (wave-private cs; noise in regs) ----
        float4 cva = *(const float4*)(&csbuf[row_l][csr0]);
        float4 cvb = *(const float4*)(&csbuf[row_l][csr1]);
        float cv[8] = {cva.x, cva.y, cva.z, cva.w, cvb.x, cvb.y, cvb.z, cvb.w};
        float nn[8] = {nA0.x, nA0.y, nA0.z, nA0.w, nA1.x, nA1.y, nA1.z, nA1.w};
        short8 v1, v2;
#pragma unroll
        for (int j = 0; j < 8; ++j) {
            float e1 = __expf(cv[j]);
            float e2 = __expf((cv[j] + nn[j]) * inv_tau);
            s1t += e1;
            s2t += e2;
            v1[j] = (short)f2bf(e1);
            v2[j] = (short)f2bf(e2);
        }
        *(short8*)(e2p + lc * 32) = v2;
        // e1 -> pbuf (union with csbuf rows; within-wave read-before-write order)
        *(short8*)((char*)&csbuf[row_l][0] + pwB) = v1;
        // rotate noise prefetch
        nA0 = nB0; nA1 = nB1;
        int nx = (lc + 2 < 17) ? (lc + 2) : 16;
        nB0 = *(const float4*)(np + nx * 32);
        nB1 = *(const float4*)(np + nx * 32 + 4);
        // ---- PV phase: A = pbuf fragment (union), B = vbuf (swizzled chunk lg ^ li&3) ----
        {
            short8 pa = *(const short8*)((const char*)&csbuf[wv * 16 + li][0] + prB);
            __builtin_amdgcn_s_setprio(1);
#pragma unroll
            for (int dt = 0; dt < 8; ++dt) {
                short8 bv = *(const short8*)(&vbuf[cur][dt * 16 + li][vro]);
                acc[dt] = mfma16(pa, bv, acc[dt]);
            }
            __builtin_amdgcn_s_setprio(0);
        }
        // stage next tile into the other buffer
        if (lc < 16) {
            *(short8*)(&kbuf[cur ^ 1][srow][kwo0]) = kn0;
            *(short8*)(&kbuf[cur ^ 1][srow][kwo1]) = kn1;
            *(short8*)(&vbuf[cur ^ 1][vrow][vwo0]) = vn0;
            *(short8*)(&vbuf[cur ^ 1][vrow][vwo1]) = vn1;
        }
        __syncthreads();
        cur ^= 1;
    }

    // 4 lanes per row -> row sums
    s1t += __shfl_xor(s1t, 1); s1t += __shfl_xor(s1t, 2);
    s2t += __shfl_xor(s2t, 1); s2t += __shfl_xor(s2t, 2);
    if ((t & 3) == 0) {
        atomicAdd(&S1[h * MM + mrow_g], s1t);
        atomicAdd(&S2[h * MM + mrow_g], s2t);
    }

    // write PV stripe partials
    const int mD = mb * 64 + wv * 16 + lg * 4;
    float* op = owsP + ((long)ls * HH + h) * MM * DD;
#pragma unroll
    for (int dt = 0; dt < 8; ++dt)
#pragma unroll
        for (int r = 0; r < 4; ++r)
            op[(long)(mD + r) * DD + dt * 16 + li] = acc[dt][r];
}

// ---- finalize: sum stripe partials, /S1 -> out; invS2 ----
__global__ __launch_bounds__(256) void finalize_o_kernel(const float* __restrict__ owsP,
    const float* __restrict__ S1, const float* __restrict__ S2,
    float* __restrict__ out, float* __restrict__ invS2) {
    int i = blockIdx.x * 256 + threadIdx.x;
    int hm = i >> 5;
    int d4 = (i & 31) * 4;
    int h = hm >> 8, m = hm & 255;
    float4 s = {0,0,0,0};
#pragma unroll
    for (int st = 0; st < NSTR; ++st) {
        const float4 v = *(const float4*)(owsP + ((long)st * HH * MM + hm) * DD + d4);
        s.x += v.x; s.y += v.y; s.z += v.z; s.w += v.w;
    }
    float inv = 1.0f / S1[hm];
    float4 o;
    o.x = s.x * inv; o.y = s.y * inv; o.z = s.z * inv; o.w = s.w * inv;
    *(float4*)(out + (long)m * NN + h * DD + d4) = o;
    if ((i & 31) == 0) invS2[hm] = 1.0f / S2[hm];
}

// ---- pass 2: c_out[h][l] = sum_m e2[h][m][l] * invS2[h][m] ----
__global__ __launch_bounds__(256) void attn_p2_kernel(const unsigned short* __restrict__ e2b,
    const float* __restrict__ invS2, float* __restrict__ cout) {
    const int h = blockIdx.y;
    const int l = blockIdx.x * 256 + threadIdx.x;
    const unsigned short* ep = e2b + (long)h * MM * LL + l;
    const float* is2 = invS2 + h * MM;
    float acc0 = 0.f, acc1 = 0.f, acc2 = 0.f, acc3 = 0.f;
    for (int m = 0; m < MM; m += 4) {
        acc0 += bf2f(__builtin_nontemporal_load(ep + (long)(m + 0) * LL)) * is2[m + 0];
        acc1 += bf2f(__builtin_nontemporal_load(ep + (long)(m + 1) * LL)) * is2[m + 1];
        acc2 += bf2f(__builtin_nontemporal_load(ep + (long)(m + 2) * LL)) * is2[m + 2];
        acc3 += bf2f(__builtin_nontemporal_load(ep + (long)(m + 3) * LL)) * is2[m + 3];
    }
    cout[(long)h * LL + l] = (acc0 + acc1) + (acc2 + acc3);
}

extern "C" void kernel_launch(void* const* d_in, const int* in_sizes, int n_in,
                              void* d_out, int out_size, void* d_ws, size_t ws_size,
                              hipStream_t stream) {
    const float* X     = (const float*)d_in[0];
    const float* Wq    = (const float*)d_in[1];
    const float* Wk    = (const float*)d_in[2];
    const float* Wv    = (const float*)d_in[3];
    const float* cK    = (const float*)d_in[4];
    const float* cV    = (const float*)d_in[5];
    const float* tau   = (const float*)d_in[6];
    const float* noise = (const float*)d_in[7];
    float* out = (float*)d_out;

    char* ws = (char*)d_ws;
    size_t off = 0;
    unsigned short* qb   = (unsigned short*)(ws + off); off += (size_t)HH * MM * DD * 2;
    unsigned short* kcat = (unsigned short*)(ws + off); off += (size_t)HH * LL * DD * 2;
    unsigned short* vT   = (unsigned short*)(ws + off); off += (size_t)HH * LL * DD * 2;
    float* S1    = (float*)(ws + off); off += (size_t)HH * MM * 4;
    float* S2    = (float*)(ws + off); off += (size_t)HH * MM * 4;
    float* invS2 = (float*)(ws + off); off += (size_t)HH * MM * 4;
    float* owsP  = (float*)(ws + off); off += (size_t)NSTR * HH * MM * DD * 4;
    unsigned short* xb = (unsigned short*)(ws + off); off += (size_t)MM * NN * 2;
    float* qkvfP = (float*)(ws + off); off += (size_t)SPL * 3 * MM * NN * 4;
    unsigned short* e2b = (unsigned short*)(ws + off); off += (size_t)HH * MM * LL * 2;

    hipMemsetAsync(S1, 0, 2 * (size_t)HH * MM * 4, stream);

    conv_x_kernel<<<512, 256, 0, stream>>>(X, xb);
    conv_k_kernel<<<8192, 256, 0, stream>>>(cK, kcat);
    conv_vt_kernel<<<dim3(64, 2, 32), 256, 0, stream>>>(cV, vT);
    proj_gemm_kernel<<<dim3(64, SPL, 3), 512, 0, stream>>>(xb, Wq, Wk, Wv, qkvfP);
    epi_qk_kernel<<<1024, 256, 0, stream>>>(qkvfP, qb, kcat);
    epi_v_kernel<<<dim3(4, 64), 256, 0, stream>>>(qkvfP, vT);
    attn_fused_kernel<<<1024, 256, 0, stream>>>(qb, kcat, vT, noise, tau, S1, S2, e2b, owsP);
    finalize_o_kernel<<<1024, 256, 0, stream>>>(owsP, S1, S2, out, invS2);
    attn_p2_kernel<<<dim3(17, 32), 256, 0, stream>>>(e2b, invS2, out + (size_t)MM * NN);
}